// Round 8
// baseline (78.383 us; speedup 1.0000x reference)
//
#include <hip/hip_runtime.h>
#include <hip/hip_bf16.h>

// ---------------------------------------------------------------------------
// Diagonal-covariance GMM log-likelihoods as one bf16 MFMA GEMM + bias:
//   out[m,k] = sum_f [ x^2 * (-0.5/cov) + x * (mu/cov) ] + bias[k]
// GEMM: M=16384, N=512 (padded from 500), K2=2048 (interleaved x^2/x pairs)
//
// R7 = R6 pipeline (pre-swizzled W image, global_load_lds width=16 one-ahead,
// A-loads one-ahead, single barrier/iter) at BM=64:
//   grid 1024 blocks, LDS 48KB/block -> 3 blocks/CU (12 waves/CU, +50%
//   independent contexts vs R6's 2). R6 was latency-bound at barriers with
//   nothing saturated (MfmaUtil 19, VALU 18, HBM 13, Occ 17).
//   acc 2x4 (32 AGPR); launch_bounds stays (256,2) — no allocator clamp
//   (R1/R4 lesson: clamping min-waves caused spill storms).
// ---------------------------------------------------------------------------

typedef __attribute__((ext_vector_type(8))) __bf16 bf16x8;
typedef __attribute__((ext_vector_type(4))) float  f32x4;

#define LOG_2PI 1.837877066409345339082f

constexpr int M_TOT = 16384;   // B*T
constexpr int F_DIM = 1024;
constexpr int K_GMM = 500;
constexpr int N_PAD = 512;

constexpr int BM  = 64;
constexpr int BN  = 128;
constexpr int BKF = 32;              // K-step in floats (=> 64 bf16 along K2)
constexpr int NIT = F_DIM / BKF;     // 32 K-steps

// async global->LDS, 16B per lane (dest = uniform base + lane*16 in HW)
__device__ __forceinline__ void gload_lds16(const void* g, void* l) {
    __builtin_amdgcn_global_load_lds(
        (const __attribute__((address_space(1))) unsigned*)g,
        (__attribute__((address_space(3))) unsigned*)l, 16, 0, 0);
}

// pack (bf16(x*x), bf16(x)) into one dword: low16 = x^2 (even K2 slot), hi16 = x
__device__ __forceinline__ unsigned pack_sq_x(float x) {
    __hip_bfloat162 h = __float22bfloat162_rn(make_float2(x * x, x));
    union { __hip_bfloat162 h; unsigned u; } cv;
    cv.h = h;
    return cv.u;
}

// ---------------------------------------------------------------------------
// prep: build the swizzled tiled W image + fp32 bias. (unchanged from R6)
// Image layout: block (t,it) at dword offset (t*32+it)*4096 holds the LDS
// image for n_tile t, K-step it: row r (0..127), logical chunk cc (0..7 of
// 8 bf16) stored at chunk position cc ^ (r&7). Element f -> it=f>>5,
// cc=(f>>2)&7, dword q=f&3 holds (bf16(-0.5/cov), bf16(mu/cov)).
// Rows k in [500,512) zeroed; bias=0 there.
// ---------------------------------------------------------------------------
__global__ __launch_bounds__(256) void prep_w_kernel(
    const float* __restrict__ mu, const float* __restrict__ cov,
    unsigned* __restrict__ Wimg, float* __restrict__ bias)
{
    const int k = blockIdx.x;           // 0..511 (component row)
    const int t = threadIdx.x;
    const int r  = k & 127;
    const int tt = k >> 7;
    const int rsw = r & 7;
    float sl = 0.f, sq = 0.f;
    #pragma unroll
    for (int j = 0; j < 4; ++j) {
        const int f  = t + j * 256;
        const int it = f >> 5;
        const int cc = (f >> 2) & 7;
        const int q  = f & 3;
        const int dw = (tt * 32 + it) * 4096 + r * 32 + ((cc ^ rsw) << 2) + q;
        if (k < K_GMM) {
            const float c = cov[k * F_DIM + f];
            const float m = mu[k * F_DIM + f];
            const float ic = 1.0f / c;
            __hip_bfloat162 h = __float22bfloat162_rn(make_float2(-0.5f * ic, m * ic));
            union { __hip_bfloat162 h; unsigned u; } cv; cv.h = h;
            Wimg[dw] = cv.u;
            sl += logf(c);
            sq += m * m * ic;
        } else {
            Wimg[dw] = 0u;
        }
    }
    #pragma unroll
    for (int off = 32; off > 0; off >>= 1) {
        sl += __shfl_down(sl, off, 64);
        sq += __shfl_down(sq, off, 64);
    }
    __shared__ float red[8];
    if ((t & 63) == 0) { red[(t >> 6) * 2] = sl; red[(t >> 6) * 2 + 1] = sq; }
    __syncthreads();
    if (t == 0) {
        const float SL = red[0] + red[2] + red[4] + red[6];
        const float SQ = red[1] + red[3] + red[5] + red[7];
        bias[k] = (k < K_GMM)
                ? (-0.5f * (F_DIM * LOG_2PI) - 0.5f * SL - 0.5f * SQ) : 0.f;
    }
}

// ---------------------------------------------------------------------------
// GEMM: 64x128 tile, 4 waves (2x2, each 32x64), mfma_f32_16x16x32_bf16.
// LDS (48KB): A dbuf at {0, 8K} (XOR-swizzled [64][64] bf16), B dbuf at
// {16K, 32K} (DMA'd pre-swizzled image blocks). One barrier/iter; all
// staging for it+1 issued before the MFMAs of it.
// 1024 blocks (3/CU by LDS); n-siblings of an m-tile are 256 apart in bid
// (same XCD mod 8) -> X panel shared via that XCD's L2/L3.
// ---------------------------------------------------------------------------
__global__ __launch_bounds__(256, 2) void gemm_kernel(
    const float* __restrict__ X, const unsigned* __restrict__ Wimg,
    const float* __restrict__ bias, float* __restrict__ out)
{
    __shared__ __align__(16) char smem[49152];
    float* ep = reinterpret_cast<float*>(smem);   // 64x128 fp32 epilogue (32KB)

    const int bid    = blockIdx.x;
    const int m_base = (bid & 255) * BM;
    const int n_tile = bid >> 8;
    const int n_base = n_tile * BN;

    const int tid  = threadIdx.x;
    const int lane = tid & 63;
    const int wv   = tid >> 6;
    const int wr   = (wv >> 1) * 32;    // wave row block (0/32)
    const int wc   = (wv & 1) * 64;     // wave col block (0/64)
    const int hi   = lane >> 4;         // 0..3
    const int lo   = lane & 15;
    const int lsw  = lo & 7;            // lane-constant fragment read swizzle

    const int sr = tid >> 2;            // A staging row 0..63
    const int sc = tid & 3;             // staging chunk pair (2 chunks each)

    const float4* Xv   = reinterpret_cast<const float4*>(X);   // X row = 256 float4
    const char*   Wimc = reinterpret_cast<const char*>(Wimg);

    f32x4 acc[2][4];
    #pragma unroll
    for (int a = 0; a < 2; ++a)
        #pragma unroll
        for (int b = 0; b < 4; ++b)
            acc[a][b] = (f32x4){0.f, 0.f, 0.f, 0.f};

    // ---- prologue: stage it=0 into buffer 0 ----
    {
        const char* g0 = Wimc + (size_t)(n_tile * 32 + 0) * 16384;
        #pragma unroll
        for (int i = 0; i < 4; ++i)
            gload_lds16(g0 + i * 4096 + wv * 1024 + lane * 16,
                        smem + 16384 + i * 4096 + wv * 1024);
        float4 a0[2];
        #pragma unroll
        for (int j = 0; j < 2; ++j)
            a0[j] = Xv[(m_base + sr) * (F_DIM / 4) + sc * 2 + j];
        unsigned short* A0 = reinterpret_cast<unsigned short*>(smem);
        #pragma unroll
        for (int j = 0; j < 2; ++j) {
            const int chunk = (sc * 2 + j) ^ (sr & 7);
            uint4 wa;
            wa.x = pack_sq_x(a0[j].x);
            wa.y = pack_sq_x(a0[j].y);
            wa.z = pack_sq_x(a0[j].z);
            wa.w = pack_sq_x(a0[j].w);
            *reinterpret_cast<uint4*>(&A0[sr * 64 + chunk * 8]) = wa;
        }
    }
    __syncthreads();   // drains DMA (vmcnt) + LDS writes

    for (int it = 0; it < NIT; ++it) {
        const int cur = it & 1;
        const int nxt = cur ^ 1;
        const unsigned short* Asc =
            reinterpret_cast<const unsigned short*>(smem + cur * 8192);
        const unsigned short* Bsc =
            reinterpret_cast<const unsigned short*>(smem + 16384 + cur * 16384);
        char*           Bdst = smem + 16384 + nxt * 16384;
        unsigned short* Adst = reinterpret_cast<unsigned short*>(smem + nxt * 8192);

        float4 a_next[2];
        if (it + 1 < NIT) {
            // B DMA for it+1 (async into Bdst) — a full MFMA phase to land
            const char* gs = Wimc + (size_t)(n_tile * 32 + it + 1) * 16384;
            #pragma unroll
            for (int i = 0; i < 4; ++i)
                gload_lds16(gs + i * 4096 + wv * 1024 + lane * 16,
                            Bdst + i * 4096 + wv * 1024);
            // A loads for it+1
            #pragma unroll
            for (int j = 0; j < 2; ++j)
                a_next[j] = Xv[(m_base + sr) * (F_DIM / 4) + (it + 1) * 8 + sc * 2 + j];
        }

        // ---- MFMAs on buffer cur ----
        #pragma unroll
        for (int c = 0; c < 2; ++c) {
            bf16x8 af[2], bf[4];
            #pragma unroll
            for (int a = 0; a < 2; ++a) {
                const int row   = wr + a * 16 + lo;
                const int chunk = (c * 4 + hi) ^ lsw;
                af[a] = *reinterpret_cast<const bf16x8*>(&Asc[row * 64 + chunk * 8]);
            }
            #pragma unroll
            for (int b = 0; b < 4; ++b) {
                const int row   = wc + b * 16 + lo;
                const int chunk = (c * 4 + hi) ^ lsw;
                bf[b] = *reinterpret_cast<const bf16x8*>(&Bsc[row * 64 + chunk * 8]);
            }
            #pragma unroll
            for (int a = 0; a < 2; ++a)
                #pragma unroll
                for (int b = 0; b < 4; ++b)
                    acc[a][b] = __builtin_amdgcn_mfma_f32_16x16x32_bf16(
                        af[a], bf[b], acc[a][b], 0, 0, 0);
        }

        if (it + 1 < NIT) {
            // convert + write A for it+1 (loads had the MFMA phase to land)
            #pragma unroll
            for (int j = 0; j < 2; ++j) {
                const int chunk = (sc * 2 + j) ^ (sr & 7);
                uint4 wa;
                wa.x = pack_sq_x(a_next[j].x);
                wa.y = pack_sq_x(a_next[j].y);
                wa.z = pack_sq_x(a_next[j].z);
                wa.w = pack_sq_x(a_next[j].w);
                *reinterpret_cast<uint4*>(&Adst[sr * 64 + chunk * 8]) = wa;
            }
        }
        __syncthreads();   // next-iter buffers ready; cur buffers free
    }

    // ---- Epilogue: acc+bias -> 32KB LDS fp32 tile -> dense coalesced rows ----
    // (final loop barrier already separates last MFMA reads from ep reuse)
    #pragma unroll
    for (int b = 0; b < 4; ++b) {
        const int col = wc + b * 16 + lo;
        const float bv = bias[n_base + col];
        #pragma unroll
        for (int a = 0; a < 2; ++a) {
            const int er = wr + a * 16 + hi * 4;  // D: col=lane&15, row=(lane>>4)*4+i
            #pragma unroll
            for (int i = 0; i < 4; ++i)
                ep[(er + i) * 128 + col] = acc[a][b][i] + bv;
        }
    }
    __syncthreads();

    const int ncols = (K_GMM - n_base < BN) ? (K_GMM - n_base) : BN;  // 128 or 116
    #pragma unroll
    for (int k = 0; k < 8; ++k) {
        const int f    = k * 256 + tid;   // float4 id in 64x32 grid
        const int row  = f >> 5;
        const int slot = f & 31;
        if (slot * 4 < ncols) {
            const float4 v = *reinterpret_cast<const float4*>(&ep[row * 128 + slot * 4]);
            *reinterpret_cast<float4*>(
                &out[(size_t)(m_base + row) * K_GMM + n_base + slot * 4]) = v;
        }
    }
}

extern "C" void kernel_launch(void* const* d_in, const int* in_sizes, int n_in,
                              void* d_out, int out_size, void* d_ws, size_t ws_size,
                              hipStream_t stream)
{
    (void)in_sizes; (void)n_in; (void)out_size; (void)ws_size;
    const float* X   = (const float*)d_in[0];
    const float* mu  = (const float*)d_in[1];
    const float* cov = (const float*)d_in[2];
    float* out = (float*)d_out;

    // workspace: W image = 512*1024 dwords (2 MiB), then bias[512] f32
    unsigned* Wimg = (unsigned*)d_ws;
    float*    bias = (float*)((char*)d_ws + (size_t)N_PAD * F_DIM * 4);

    prep_w_kernel<<<dim3(N_PAD), dim3(256), 0, stream>>>(mu, cov, Wimg, bias);
    gemm_kernel<<<dim3((M_TOT / BM) * (N_PAD / BN)), dim3(256), 0, stream>>>(X, Wimg, bias, out);
}

// Round 9
// 54.596 us; speedup vs baseline: 1.4357x; 1.4357x over previous
//
#include <hip/hip_runtime.h>
#include <hip/hip_bf16.h>

// ---------------------------------------------------------------------------
// Diagonal-covariance GMM log-likelihoods as one bf16 MFMA GEMM + bias:
//   out[m,k] = sum_f [ x^2 * (-0.5/cov) + x * (mu/cov) ] + bias[k]
// GEMM: M=16384, N=512 (padded from 500), K2=2048 (interleaved x^2/x pairs)
//
// R8 = R6 geometry (128x128, 512 blocks, (256,2)) + T4 counted-vmcnt pipeline:
//   - B: 3 LDS buffers, global_load_lds DMA issued TWO iterations ahead.
//   - A: X loads two ahead (ping-pong regs, unroll-2), pack+ds_write one ahead.
//   - Barrier = s_waitcnt vmcnt(8) lgkmcnt(0) + raw s_barrier (+sched_barrier);
//     the newest 8 stage ops stay in flight across the barrier. Drain only in
//     the final pair. R6's __syncthreads drained vmcnt(0) every iter -> the
//     staging latency was exposed; that was the measured stall (all pipes idle).
//   R7 lesson (twice): BM=64 inflates FETCH (X re-reads) — keep BM=128.
// ---------------------------------------------------------------------------

typedef __attribute__((ext_vector_type(8))) __bf16 bf16x8;
typedef __attribute__((ext_vector_type(4))) float  f32x4;

#define LOG_2PI 1.837877066409345339082f

constexpr int M_TOT = 16384;   // B*T
constexpr int F_DIM = 1024;
constexpr int K_GMM = 500;
constexpr int N_PAD = 512;

constexpr int BM  = 128;
constexpr int BN  = 128;
constexpr int BKF = 32;              // K-step in floats (=> 64 bf16 along K2)
constexpr int NIT = F_DIM / BKF;     // 32 K-steps

// async global->LDS, 16B per lane (dest = uniform base + lane*16 in HW)
__device__ __forceinline__ void gload_lds16(const void* g, void* l) {
    __builtin_amdgcn_global_load_lds(
        (const __attribute__((address_space(1))) unsigned*)g,
        (__attribute__((address_space(3))) unsigned*)l, 16, 0, 0);
}

// pack (bf16(x*x), bf16(x)) into one dword: low16 = x^2 (even K2 slot), hi16 = x
__device__ __forceinline__ unsigned pack_sq_x(float x) {
    __hip_bfloat162 h = __float22bfloat162_rn(make_float2(x * x, x));
    union { __hip_bfloat162 h; unsigned u; } cv;
    cv.h = h;
    return cv.u;
}

// ---------------------------------------------------------------------------
// prep: build the swizzled tiled W image + fp32 bias. (unchanged from R6)
// Block (t,it) at dword offset (t*32+it)*4096 = LDS image for n_tile t,
// K-step it: row r (0..127), logical chunk cc stored at cc ^ (r&7).
// Element f -> it=f>>5, cc=(f>>2)&7, q=f&3: (bf16(-0.5/cov), bf16(mu/cov)).
// Rows k in [500,512) zeroed; bias=0 there.
// ---------------------------------------------------------------------------
__global__ __launch_bounds__(256) void prep_w_kernel(
    const float* __restrict__ mu, const float* __restrict__ cov,
    unsigned* __restrict__ Wimg, float* __restrict__ bias)
{
    const int k = blockIdx.x;           // 0..511 (component row)
    const int t = threadIdx.x;
    const int r  = k & 127;
    const int tt = k >> 7;
    const int rsw = r & 7;
    float sl = 0.f, sq = 0.f;
    #pragma unroll
    for (int j = 0; j < 4; ++j) {
        const int f  = t + j * 256;
        const int it = f >> 5;
        const int cc = (f >> 2) & 7;
        const int q  = f & 3;
        const int dw = (tt * 32 + it) * 4096 + r * 32 + ((cc ^ rsw) << 2) + q;
        if (k < K_GMM) {
            const float c = cov[k * F_DIM + f];
            const float m = mu[k * F_DIM + f];
            const float ic = 1.0f / c;
            __hip_bfloat162 h = __float22bfloat162_rn(make_float2(-0.5f * ic, m * ic));
            union { __hip_bfloat162 h; unsigned u; } cv; cv.h = h;
            Wimg[dw] = cv.u;
            sl += logf(c);
            sq += m * m * ic;
        } else {
            Wimg[dw] = 0u;
        }
    }
    #pragma unroll
    for (int off = 32; off > 0; off >>= 1) {
        sl += __shfl_down(sl, off, 64);
        sq += __shfl_down(sq, off, 64);
    }
    __shared__ float red[8];
    if ((t & 63) == 0) { red[(t >> 6) * 2] = sl; red[(t >> 6) * 2 + 1] = sq; }
    __syncthreads();
    if (t == 0) {
        const float SL = red[0] + red[2] + red[4] + red[6];
        const float SQ = red[1] + red[3] + red[5] + red[7];
        bias[k] = (k < K_GMM)
                ? (-0.5f * (F_DIM * LOG_2PI) - 0.5f * SL - 0.5f * SQ) : 0.f;
    }
}

// ---------------------------------------------------------------------------
// GEMM: 128x128 tile, 4 waves (2x2, each 64x64), mfma_f32_16x16x32_bf16.
// LDS 80KB: A dbuf at {0,16K} (XOR-swizzled [128][64] bf16), B tri-buf at
// {32K,48K,64K} (DMA'd pre-swizzled image blocks). Counted-vmcnt barriers.
// 512 blocks (2/CU); n-siblings of an m-tile are 128 apart in bid (same XCD).
// ---------------------------------------------------------------------------
__global__ __launch_bounds__(256, 2) void gemm_kernel(
    const float* __restrict__ X, const unsigned* __restrict__ Wimg,
    const float* __restrict__ bias, float* __restrict__ out)
{
    __shared__ __align__(16) char smem[81920];
    float* ep = reinterpret_cast<float*>(smem);   // 64x128 fp32 epilogue (32KB)

    const int bid    = blockIdx.x;
    const int m_base = (bid & 127) * BM;
    const int n_tile = bid >> 7;
    const int n_base = n_tile * BN;

    const int tid  = threadIdx.x;
    const int lane = tid & 63;
    const int wv   = tid >> 6;
    const int wr   = (wv >> 1) * 64;    // wave row block (0/64)
    const int wc   = (wv & 1) * 64;     // wave col block (0/64)
    const int hi   = lane >> 4;         // 0..3
    const int lo   = lane & 15;
    const int lsw  = lo & 7;            // lane-constant fragment read swizzle

    const int sr = tid >> 1;            // A staging row 0..127
    const int sh = tid & 1;             // staging half (chunks 0-3 / 4-7)

    const float4* Xv   = reinterpret_cast<const float4*>(X);   // X row = 256 float4
    const char*   Wimc = reinterpret_cast<const char*>(Wimg);

    f32x4 acc[4][4];
    #pragma unroll
    for (int a = 0; a < 4; ++a)
        #pragma unroll
        for (int b = 0; b < 4; ++b)
            acc[a][b] = (f32x4){0.f, 0.f, 0.f, 0.f};

    // ---- pipeline helper lambdas ----
    auto stageB = [&](int itS, int bufS) {            // 4 async DMA, 16KB total
        const char* gs = Wimc + (size_t)(n_tile * 32 + itS) * 16384;
        #pragma unroll
        for (int i = 0; i < 4; ++i)
            gload_lds16(gs + i * 4096 + wv * 1024 + lane * 16,
                        smem + 32768 + bufS * 16384 + i * 4096 + wv * 1024);
    };
    auto loadA = [&](int itS, float4* ar) {           // 4 global float4
        #pragma unroll
        for (int j = 0; j < 4; ++j)
            ar[j] = Xv[(m_base + sr) * (F_DIM / 4) + itS * 8 + sh * 4 + j];
    };
    auto packA = [&](const float4* ar, int ab) {      // pack + swizzled ds_write
        unsigned short* Ad = reinterpret_cast<unsigned short*>(smem + ab * 16384);
        #pragma unroll
        for (int j = 0; j < 4; ++j) {
            const int chunk = (sh * 4 + j) ^ (sr & 7);
            uint4 wa;
            wa.x = pack_sq_x(ar[j].x);
            wa.y = pack_sq_x(ar[j].y);
            wa.z = pack_sq_x(ar[j].z);
            wa.w = pack_sq_x(ar[j].w);
            *reinterpret_cast<uint4*>(&Ad[sr * 64 + chunk * 8]) = wa;
        }
    };
    auto compute = [&](int ab, int bb) {              // 16 ds_read_b128, 32 MFMA
        const unsigned short* Asc =
            reinterpret_cast<const unsigned short*>(smem + ab * 16384);
        const unsigned short* Bsc =
            reinterpret_cast<const unsigned short*>(smem + 32768 + bb * 16384);
        #pragma unroll
        for (int c = 0; c < 2; ++c) {
            bf16x8 af[4], bf[4];
            #pragma unroll
            for (int a = 0; a < 4; ++a) {
                const int row   = wr + a * 16 + lo;
                const int chunk = (c * 4 + hi) ^ lsw;
                af[a] = *reinterpret_cast<const bf16x8*>(&Asc[row * 64 + chunk * 8]);
            }
            #pragma unroll
            for (int b = 0; b < 4; ++b) {
                const int row   = wc + b * 16 + lo;
                const int chunk = (c * 4 + hi) ^ lsw;
                bf[b] = *reinterpret_cast<const bf16x8*>(&Bsc[row * 64 + chunk * 8]);
            }
            #pragma unroll
            for (int a = 0; a < 4; ++a)
                #pragma unroll
                for (int b = 0; b < 4; ++b)
                    acc[a][b] = __builtin_amdgcn_mfma_f32_16x16x32_bf16(
                        af[a], bf[b], acc[a][b], 0, 0, 0);
        }
    };

    // ---- prologue: stage it=0 and it=1; pack A(0); counted barrier ----
    float4 aA[4], aB[4];
    stageB(0, 0);
    loadA(0, aB);
    stageB(1, 1);
    loadA(1, aA);          // aA = A(1) for the loop
    packA(aB, 0);          // A(0) -> Abuf0 (auto-waits its own loads)
    asm volatile("s_waitcnt vmcnt(8) lgkmcnt(0)" ::: "memory");  // it0 staging done; it1's flies
    __builtin_amdgcn_s_barrier();
    __builtin_amdgcn_sched_barrier(0);

    // ---- main loop: unroll-2 for static aA/aB ping-pong; B buffer = it%3 ----
    for (int it = 0; it < NIT; it += 2) {
        const int b0 = it % 3;
        const int b1 = (it + 1) % 3;
        const int b2 = (it + 2) % 3;
        const int b3 = (it + 3) % 3;

        // ===== iter it: compute Abuf0 / Bbuf[b0] =====
        if (it + 2 < NIT) { stageB(it + 2, b2); loadA(it + 2, aB); }
        compute(0, b0);
        packA(aA, 1);                       // A(it+1) -> Abuf1
        if (it + 2 < NIT)
            asm volatile("s_waitcnt vmcnt(8) lgkmcnt(0)" ::: "memory");
        else
            asm volatile("s_waitcnt vmcnt(0) lgkmcnt(0)" ::: "memory");
        __builtin_amdgcn_s_barrier();
        __builtin_amdgcn_sched_barrier(0);

        // ===== iter it+1: compute Abuf1 / Bbuf[b1] =====
        if (it + 3 < NIT) { stageB(it + 3, b3); loadA(it + 3, aA); }
        compute(1, b1);
        if (it + 2 < NIT) packA(aB, 0);     // A(it+2) -> Abuf0
        if (it + 3 < NIT)
            asm volatile("s_waitcnt vmcnt(8) lgkmcnt(0)" ::: "memory");
        else
            asm volatile("s_waitcnt vmcnt(0) lgkmcnt(0)" ::: "memory");
        __builtin_amdgcn_s_barrier();
        __builtin_amdgcn_sched_barrier(0);
    }

    // ---- Epilogue: two 64-row passes; acc+bias -> LDS -> dense row writes ----
    // (final loop barrier already separates last ds_reads from ep reuse)
    const int ncols = (K_GMM - n_base < BN) ? (K_GMM - n_base) : BN;  // 128 or 116
    #pragma unroll
    for (int p = 0; p < 2; ++p) {
        if (p) __syncthreads();        // pass-0 reads done before pass-1 writes
        if ((wv >> 1) == p) {          // the 2 waves owning row-half p dump acc
            #pragma unroll
            for (int b = 0; b < 4; ++b) {
                const int col = wc + b * 16 + lo;
                const float bv = bias[n_base + col];
                #pragma unroll
                for (int a = 0; a < 4; ++a)
                    #pragma unroll
                    for (int i = 0; i < 4; ++i)
                        ep[(a * 16 + hi * 4 + i) * 128 + col] = acc[a][b][i] + bv;
            }
        }
        __syncthreads();
        #pragma unroll
        for (int k = 0; k < 8; ++k) {
            const int f    = k * 256 + tid;   // float4 id in 64x32 grid
            const int row  = f >> 5;
            const int slot = f & 31;
            if (slot * 4 < ncols) {
                const float4 v = *reinterpret_cast<const float4*>(&ep[row * 128 + slot * 4]);
                *reinterpret_cast<float4*>(
                    &out[(size_t)(m_base + p * 64 + row) * K_GMM + n_base + slot * 4]) = v;
            }
        }
    }
}

extern "C" void kernel_launch(void* const* d_in, const int* in_sizes, int n_in,
                              void* d_out, int out_size, void* d_ws, size_t ws_size,
                              hipStream_t stream)
{
    (void)in_sizes; (void)n_in; (void)out_size; (void)ws_size;
    const float* X   = (const float*)d_in[0];
    const float* mu  = (const float*)d_in[1];
    const float* cov = (const float*)d_in[2];
    float* out = (float*)d_out;

    // workspace: W image = 512*1024 dwords (2 MiB), then bias[512] f32
    unsigned* Wimg = (unsigned*)d_ws;
    float*    bias = (float*)((char*)d_ws + (size_t)N_PAD * F_DIM * 4);

    prep_w_kernel<<<dim3(N_PAD), dim3(256), 0, stream>>>(mu, cov, Wimg, bias);
    gemm_kernel<<<dim3((M_TOT / BM) * (N_PAD / BN)), dim3(256), 0, stream>>>(X, Wimg, bias, out);
}